// Round 6
// baseline (353.166 us; speedup 1.0000x reference)
//
#include <hip/hip_runtime.h>
#include <hip/hip_bf16.h>
#include <stdint.h>

typedef _Float16 f16;
typedef _Float16 f16x4 __attribute__((ext_vector_type(4)));
typedef _Float16 f16x8 __attribute__((ext_vector_type(8)));
typedef float f32x4 __attribute__((ext_vector_type(4)));

// async global->LDS copy, 16B per lane. LDS dest must be wave-uniform-base + lane*16.
#define ASYNC_COPY16(gsrc, ldst)                                                   \
    __builtin_amdgcn_global_load_lds(                                              \
        (__attribute__((address_space(1))) void*)(gsrc),                           \
        (__attribute__((address_space(3))) void*)(ldst), 16, 0, 0)

#define MFMA16(a, b, c) __builtin_amdgcn_mfma_f32_16x16x32_f16((a), (b), (c), 0, 0, 0)

// ---------------------------------------------------------------------------
// fp32 -> f16 conversion, 4 elems/thread (float4 load, 8B store)
// ---------------------------------------------------------------------------
__global__ __launch_bounds__(256) void cvt_f32_to_f16(const float* __restrict__ in,
                                                      f16* __restrict__ out, int n4) {
    int i = blockIdx.x * 256 + threadIdx.x;
    if (i >= n4) return;
    float4 v = ((const float4*)in)[i];
    f16x4 o;
    o.x = (f16)v.x; o.y = (f16)v.y; o.z = (f16)v.z; o.w = (f16)v.w;
    ((f16x4*)out)[i] = o;
}

// three conversions in one launch: y -> yb, W1 -> w1b, W2 -> w2b
__global__ __launch_bounds__(256) void cvt3_f32_to_f16(const float* __restrict__ y,
                                                       const float* __restrict__ W1,
                                                       const float* __restrict__ W2,
                                                       f16* __restrict__ yb,
                                                       f16* __restrict__ w1b,
                                                       f16* __restrict__ w2b,
                                                       int nY4, int nW4) {
    int i = blockIdx.x * 256 + threadIdx.x;
    const float* src;
    f16* dst;
    int off;
    if (i < nY4) {
        src = y; dst = yb; off = i;
    } else if (i < nY4 + nW4) {
        src = W1; dst = w1b; off = i - nY4;
    } else {
        src = W2; dst = w2b; off = i - nY4 - nW4;
        if (off >= nW4) return;
    }
    float4 v = ((const float4*)src)[off];
    f16x4 o;
    o.x = (f16)v.x; o.y = (f16)v.y; o.z = (f16)v.z; o.w = (f16)v.w;
    ((f16x4*)dst)[off] = o;
}

// ---------------------------------------------------------------------------
// C = A(MxK) * B(NxK)^T + bias, f16 in, fp32 accumulate.
//
// ROUND-5 DIAGNOSIS: two radically different intra-block schedules (lockstep
// 4-barrier vs 1-barrier deferred-MFMA pipeline) measured IDENTICAL
// (80.9 vs 81.9 us, MfmaUtil 34% both) => not schedule-bound. All variants
// so far ran 8 waves/CU; m97/m103 hits 912 TF with the SIMPLE schedule at
// 12 waves/CU (3 blocks/CU): cross-BLOCK TLP covers the barrier drain
// (m114). Counters (all pipes idle, occupancy 19.5%) = latency-bound.
//
// THIS ROUND: occupancy 8 -> 16 waves/CU.
//   Tile 128x128, BK=64, 512 thr = 8 waves (2M x 4N), per-wave 64x32
//   (4x2 16x16x32 frags). LDS = double-buffer 2x(16+16) = 64 KB
//   -> 2 blocks/CU. grid (N/128)x(M/128) = 32x16 = 512 blocks = 2/CU
//   -> 16 waves/CU (4/SIMD). While one block drains its tile barrier,
//   the co-resident block computes.
//   Schedule: proven round-1 structure, ONE full drain + barrier per tile:
//     s_waitcnt(0); barrier; prefetch(next -> buf^1); compute buf[cur].
//   (s_waitcnt(0) before barrier: LDS-DMA vmcnt drain must not depend on
//   compiler's global_load_lds modeling at barriers - round-0 race class.)
//
// LDS rows are 128 B; XOR swizzle (seg ^= row&7) applied on the GLOBAL source
// (global_load_lds forces linear LDS writes) and undone at ds_read
// (measured: SQ_LDS_BANK_CONFLICT = 0 with this scheme).
// STORE_F16: 1 -> f16 output (h), 0 -> fp32 output.
// ---------------------------------------------------------------------------
template <int STORE_F16>
__global__ __launch_bounds__(512, 4) void gemm_bt(const f16* __restrict__ A,
                                                  const f16* __restrict__ Bm,
                                                  const float* __restrict__ bias,
                                                  void* __restrict__ Cout,
                                                  int M, int N, int K) {
    constexpr int BM = 128, BN = 128, BK = 64;
    __shared__ __align__(16) f16 sA[2][BM * BK];  // 2 x 16 KB
    __shared__ __align__(16) f16 sB[2][BN * BK];  // 2 x 16 KB

    const int tid   = threadIdx.x;
    const int lane  = tid & 63;
    const int wave  = tid >> 6;   // 0..7
    const int waveM = wave >> 2;  // 0..1 -> 64-row slice
    const int waveN = wave & 3;   // 0..3 -> 32-col slice

    const int bm = blockIdx.y * BM;
    const int bn = blockIdx.x * BN;

    const f16* Aptr = A + (size_t)bm * K;
    const f16* Bptr = Bm + (size_t)bn * K;

    // staging: one sweep = 512 thr x 16B = 8 KB = 64 rows of 128 B.
    // A tile = 2 sweeps, B tile = 2 sweeps. Thread t writes LDS bytes
    // [s*8192 + t*16, +16) (linear per wave as global_load_lds requires);
    // global segment is XOR-swizzled: seg = (t&7) ^ (row&7).
    const int srow = tid >> 3;  // 0..63
    const int sseg = tid & 7;

    const f16* gA[2];
    const f16* gB[2];
#pragma unroll
    for (int s = 0; s < 2; s++) {
        const int row = s * 64 + srow;
        const int seg = sseg ^ (row & 7);
        gA[s] = Aptr + (size_t)row * K + seg * 8;
        gB[s] = Bptr + (size_t)row * K + seg * 8;
    }
    const int ldst = tid * 8;  // f16 elements (= tid*16 bytes)

#define STAGE_A(s, buf, k0) ASYNC_COPY16(gA[s] + (k0), &sA[buf][(s)*4096 + ldst])
#define STAGE_B(s, buf, k0) ASYNC_COPY16(gB[s] + (k0), &sB[buf][(s)*4096 + ldst])

    f32x4 acc[4][2] = {};

    const int quad = lane >> 4;
    const int l16  = lane & 15;

    const int iters = K / BK;  // 64

    // ---- prologue: stage tile 0 into buf 0 (4 loads/thread)
#pragma unroll
    for (int s = 0; s < 2; s++) STAGE_A(s, 0, 0);
#pragma unroll
    for (int s = 0; s < 2; s++) STAGE_B(s, 0, 0);

    int cur = 0;
    for (int t = 0; t < iters; ++t) {
        // full drain (vmcnt covers LDS-DMA; lgkm covers prior ds_reads) then
        // publish: buf[cur] ready for all waves, buf[cur^1] reads all done.
        __builtin_amdgcn_s_waitcnt(0);
        __syncthreads();

        // prefetch next tile into buf[cur^1] (in flight during compute)
        if (t + 1 < iters) {
            const int k0 = (t + 1) * BK;
#pragma unroll
            for (int s = 0; s < 2; s++) STAGE_A(s, cur ^ 1, k0);
#pragma unroll
            for (int s = 0; s < 2; s++) STAGE_B(s, cur ^ 1, k0);
        }

        // compute from buf[cur]: 2 k-halves of 32, 8 MFMAs each
#pragma unroll
        for (int h = 0; h < 2; h++) {
            f16x8 af[4], bf[2];
#pragma unroll
            for (int mi = 0; mi < 4; mi++) {
                const int row = waveM * 64 + mi * 16 + l16;
                const int seg = (h * 4 + quad) ^ (l16 & 7);
                af[mi] = *(const f16x8*)&sA[cur][row * BK + seg * 8];
            }
#pragma unroll
            for (int ni = 0; ni < 2; ni++) {
                const int row = waveN * 32 + ni * 16 + l16;
                const int seg = (h * 4 + quad) ^ (l16 & 7);
                bf[ni] = *(const f16x8*)&sB[cur][row * BK + seg * 8];
            }
#pragma unroll
            for (int mi = 0; mi < 4; mi++)
#pragma unroll
                for (int ni = 0; ni < 2; ni++)
                    acc[mi][ni] = MFMA16(af[mi], bf[ni], acc[mi][ni]);
        }
        cur ^= 1;
        // no second barrier: next iteration's full drain + barrier guarantees
        // all ds_reads of buf[cur] completed before any wave's prefetch
        // overwrites it.
    }

#undef STAGE_A
#undef STAGE_B

    // epilogue: C/D layout col = lane&15, row = quad*4 + reg
#pragma unroll
    for (int ni = 0; ni < 2; ni++) {
        const int col = bn + waveN * 32 + ni * 16 + l16;
        const float bv = bias[col];
#pragma unroll
        for (int mi = 0; mi < 4; mi++) {
            const int row0 = bm + waveM * 64 + mi * 16 + quad * 4;
#pragma unroll
            for (int r = 0; r < 4; r++) {
                float v = acc[mi][ni][r] + bv;
                if (STORE_F16)
                    ((f16*)Cout)[(size_t)(row0 + r) * N + col] = (f16)v;
                else
                    ((float*)Cout)[(size_t)(row0 + r) * N + col] = v;
            }
        }
    }
}

// ---------------------------------------------------------------------------
// replicator: per row r, dot = sum_k y*out; out = y*(out - dot). In-place.
// one block (256 thr) per row, float4 loads; second pass mostly L2-hits.
// ---------------------------------------------------------------------------
__global__ __launch_bounds__(256) void replicator(const float* __restrict__ y,
                                                  float* __restrict__ out, int N) {
    const int row = blockIdx.x;
    const float4* y4 = (const float4*)(y + (size_t)row * N);
    float4* o4 = (float4*)(out + (size_t)row * N);
    const int n4 = N / 4;

    float p = 0.f;
    for (int i = threadIdx.x; i < n4; i += 256) {
        float4 a = y4[i], b = o4[i];
        p += a.x * b.x + a.y * b.y + a.z * b.z + a.w * b.w;
    }
#pragma unroll
    for (int off = 32; off > 0; off >>= 1) p += __shfl_down(p, off, 64);

    __shared__ float sred[4];
    if ((threadIdx.x & 63) == 0) sred[threadIdx.x >> 6] = p;
    __syncthreads();
    const float dot = sred[0] + sred[1] + sred[2] + sred[3];

    for (int i = threadIdx.x; i < n4; i += 256) {
        float4 a = y4[i], b = o4[i];
        float4 r;
        r.x = a.x * (b.x - dot);
        r.y = a.y * (b.y - dot);
        r.z = a.z * (b.z - dot);
        r.w = a.w * (b.w - dot);
        o4[i] = r;
    }
}

extern "C" void kernel_launch(void* const* d_in, const int* in_sizes, int n_in,
                              void* d_out, int out_size, void* d_ws, size_t ws_size,
                              hipStream_t stream) {
    // inputs: 0=t(1), 1=y(B*N), 2=W1(N*N), 3=b1(N), 4=W2(N*N), 5=b2(N)
    const float* y  = (const float*)d_in[1];
    const float* W1 = (const float*)d_in[2];
    const float* b1 = (const float*)d_in[3];
    const float* W2 = (const float*)d_in[4];
    const float* b2 = (const float*)d_in[5];

    const int N = in_sizes[3];            // 4096
    const int B = in_sizes[1] / N;        // 2048
    float* out = (float*)d_out;

    const size_t szY = (size_t)B * N;     // elements
    const size_t szW = (size_t)N * N;

    const int yn4 = (int)(szY / 4);
    const int wn4 = (int)(szW / 4);

    dim3 g1(N / 128, B / 128);            // 32 x 16 = 512 blocks, 8 waves each

    const size_t need_big = (szY + 2 * szW + szY) * sizeof(f16);  // yb|w1b|w2b|hb

    if (ws_size >= need_big) {
        f16* yb  = (f16*)d_ws;
        f16* w1b = yb + szY;
        f16* w2b = w1b + szW;
        f16* hb  = w2b + szW;

        const int tot4 = yn4 + 2 * wn4;
        cvt3_f32_to_f16<<<(tot4 + 255) / 256, 256, 0, stream>>>(y, W1, W2, yb, w1b, w2b,
                                                                yn4, wn4);
        gemm_bt<1><<<g1, 512, 0, stream>>>(yb, w1b, b1, hb, B, N, N);
        gemm_bt<0><<<g1, 512, 0, stream>>>(hb, w2b, b2, out, B, N, N);
    } else {
        // fallback: reuse one weight buffer (yb | wb | hb)
        f16* yb = (f16*)d_ws;
        f16* wb = yb + szY;
        f16* hb = wb + szW;

        cvt_f32_to_f16<<<yn4 / 256, 256, 0, stream>>>(y, yb, yn4);
        cvt_f32_to_f16<<<wn4 / 256, 256, 0, stream>>>(W1, wb, wn4);
        gemm_bt<1><<<g1, 512, 0, stream>>>(yb, wb, b1, hb, B, N, N);
        cvt_f32_to_f16<<<wn4 / 256, 256, 0, stream>>>(W2, wb, wn4);
        gemm_bt<0><<<g1, 512, 0, stream>>>(hb, wb, b2, out, B, N, N);
    }

    replicator<<<B, 256, 0, stream>>>(y, out, N);
}